// Round 4
// baseline (447.924 us; speedup 1.0000x reference)
//
#include <hip/hip_runtime.h>
#include <cstdint>
#include <cstddef>

// Problem constants (from reference): N=50000, E=800000, IN=512, HID=256, MID=128, OUT=64
#define F_IN  512
#define F_HID 256
#define F_MID 128
#define F_OUT 64

typedef __attribute__((ext_vector_type(8))) short short8;   // 8 x bf16 (4 VGPRs)
typedef __attribute__((ext_vector_type(4))) float floatx4;  // MFMA accumulator

// async global->LDS, 16B per lane; LDS dst is wave-uniform base + lane*16 (m104)
#define GLD_LDS16(gp, lp) \
  __builtin_amdgcn_global_load_lds((const __attribute__((address_space(1))) void*)(gp), \
                                   (__attribute__((address_space(3))) void*)(lp), 16, 0, 0)

static __device__ __forceinline__ float b2f(ushort u) {
  union { unsigned u; float f; } v; v.u = ((unsigned)u) << 16; return v.f;
}
static __device__ __forceinline__ ushort f2b(float f) {
  union { float f; unsigned u; } v; v.f = f;
  unsigned r = v.u + 0x7fffu + ((v.u >> 16) & 1u);  // round-to-nearest-even
  return (ushort)(r >> 16);
}

// ---------------- CSR build ----------------

__global__ __launch_bounds__(256) void hist_kernel(const int* __restrict__ dst,
                                                   int* __restrict__ cnt, int e) {
  int i = blockIdx.x * 256 + threadIdx.x;
  if (i < e) atomicAdd(&cnt[dst[i]], 1);
}

__global__ __launch_bounds__(256) void dinv_kernel(const int* __restrict__ cnt,
                                                   float* __restrict__ dinv, int n) {
  int i = blockIdx.x * 256 + threadIdx.x;
  if (i < n) dinv[i] = rsqrtf(1.0f + (float)cnt[i]);  // deg includes self-loop
}

// hierarchical scan: (1) per-block exclusive scan + partial; zeroes cnt for cursor reuse
__global__ __launch_bounds__(1024) void scan1_kernel(int* __restrict__ cnt,
                                                     int* __restrict__ rp,
                                                     int* __restrict__ part, int n) {
  __shared__ int buf[1024];
  int tid = threadIdx.x;
  int i = blockIdx.x * 1024 + tid;
  int v = (i < n) ? cnt[i] : 0;
  buf[tid] = v;
  __syncthreads();
  for (int off = 1; off < 1024; off <<= 1) {
    int t = (tid >= off) ? buf[tid - off] : 0;
    __syncthreads();
    buf[tid] += t;
    __syncthreads();
  }
  if (i < n) { rp[i] = buf[tid] - v; cnt[i] = 0; }
  if (tid == 1023) part[blockIdx.x] = buf[1023];
}

// (2) scan of block partials (nb <= 1024), also writes rp[n] = total (== E)
__global__ __launch_bounds__(1024) void scan2_kernel(int* __restrict__ part,
                                                     int* __restrict__ rp, int nb, int n) {
  __shared__ int buf[1024];
  int tid = threadIdx.x;
  int v = (tid < nb) ? part[tid] : 0;
  buf[tid] = v;
  __syncthreads();
  for (int off = 1; off < 1024; off <<= 1) {
    int t = (tid >= off) ? buf[tid - off] : 0;
    __syncthreads();
    buf[tid] += t;
    __syncthreads();
  }
  if (tid < nb) part[tid] = buf[tid] - v;   // exclusive block offsets
  if (tid == nb - 1) rp[n] = buf[tid];      // total
}

// (3) add block offsets
__global__ __launch_bounds__(1024) void scan3_kernel(const int* __restrict__ part,
                                                     int* __restrict__ rp, int n) {
  int b = blockIdx.x;
  int i = b * 1024 + threadIdx.x;
  if (b > 0 && i < n) rp[i] += part[b];
}

__global__ __launch_bounds__(256) void fill_kernel(const int* __restrict__ src,
                                                   const int* __restrict__ dst,
                                                   const int* __restrict__ rp,
                                                   int* __restrict__ cur,
                                                   int* __restrict__ srcs, int e) {
  int i = blockIdx.x * 256 + threadIdx.x;
  if (i < e) {
    int d = dst[i];
    int p = rp[d] + atomicAdd(&cur[d], 1);
    srcs[p] = src[i];
  }
}

// W (f32, [K][F]) -> WT (bf16, [F][K])
__global__ __launch_bounds__(256) void transpose_kernel(const float* __restrict__ W,
                                                        ushort* __restrict__ WT,
                                                        int K, int F) {
  int i = blockIdx.x * 256 + threadIdx.x;
  if (i < K * F) {
    int k = i / F, f = i - k * F;
    WT[(size_t)f * K + k] = f2b(W[i]);
  }
}

// ---------------- MFMA GEMM: C[M,F] = A[M,K] * B[K,F], BT given as bf16 [F][K] ----------------
// block tile 128(M) x 128(N); 4 waves in 2x2, each 64x64 via 4x4 mfma_f32_16x16x32_bf16.
// Staging via global_load_lds (16B/lane, async, no VGPR round trip). OOB rows/cols are
// index-CLAMPED (garbage only feeds unstored C rows/cols; no NaN since clamped data is valid).
// LDS is XOR-swizzled at 16B-chunk granularity: phys chunk p of row r holds global chunk
// p ^ (r & (CH-1)), CH = chunks/row. Needed because global_load_lds forces contiguous
// lane*16 placement (no padding possible) and unswizzled f32 rows (128B) alias all 32 banks.
// A_F32: A tile staged as f32, converted to bf16 at fragment read (hidden under HBM latency).
template<bool A_F32, bool OUT_F32>
__global__ __launch_bounds__(256) void gemm_bt(const void* __restrict__ Av,
                                               const ushort* __restrict__ BT,
                                               const float* __restrict__ bias,
                                               void* __restrict__ Cv,
                                               int M, int K, int F) {
  __shared__ float  Asf[A_F32 ? 128 * 32 : 8];   // f32 tile: 16 KB
  __shared__ ushort Asb[A_F32 ? 8 : 128 * 32];   // bf16 tile: 8 KB
  __shared__ ushort Bs[128 * 32];                // 8 KB
  const int tid = threadIdx.x, lane = tid & 63, wv = tid >> 6;
  const int bm = blockIdx.x << 7, bn = blockIdx.y << 7;
  const int q = lane >> 4, ml = lane & 15;
  const int wm = (wv & 1) << 6, wn = (wv >> 1) << 6;

  // ---- B staging (bf16, 64B rows, 4 chunks): 2 instrs/wave, 16 rows each ----
  const int bsrow = lane >> 2;                  // 0..15
  const int bgo = ((lane & 3) ^ (bsrow & 3)) << 3;  // global elem offset (swizzled)
  int br0 = bn + wv * 32 + bsrow, br1 = br0 + 16;
  br0 = min(br0, F - 1); br1 = min(br1, F - 1);
  ushort* BsU0 = Bs + (wv * 32) * 32;
  ushort* BsU1 = Bs + (wv * 32 + 16) * 32;

  // ---- A staging ----
  // f32 (128B rows, 8 chunks): 4 instrs/wave, 8 rows each
  const int fsrow = lane >> 3;                  // 0..7
  const int fgo = ((lane & 7) ^ fsrow) << 2;    // global f32-elem offset (swizzled)
  int ar0, ar1, ar2, ar3;
  if (A_F32) {
    ar0 = min(bm + wv * 32 + fsrow,      M - 1);
    ar1 = min(bm + wv * 32 + 8 + fsrow,  M - 1);
    ar2 = min(bm + wv * 32 + 16 + fsrow, M - 1);
    ar3 = min(bm + wv * 32 + 24 + fsrow, M - 1);
  } else {
    ar0 = min(bm + wv * 32 + bsrow,      M - 1);
    ar1 = min(bm + wv * 32 + 16 + bsrow, M - 1);
    ar2 = ar3 = 0;
  }
  float*  AfU0 = Asf + (wv * 32) * 32;      float* AfU1 = Asf + (wv * 32 + 8) * 32;
  float*  AfU2 = Asf + (wv * 32 + 16) * 32; float* AfU3 = Asf + (wv * 32 + 24) * 32;
  ushort* AbU0 = Asb + (wv * 32) * 32;      ushort* AbU1 = Asb + (wv * 32 + 16) * 32;

  // ---- fragment-read swizzle constants (per lane) ----
  const int qs_b = (q ^ (ml & 3)) << 3;         // bf16: swizzled chunk -> elem offset
  const int qf_lo = ((2 * q) ^ (ml & 7)) << 2;  // f32 lo chunk -> elem offset
  const int qf_hi = ((2 * q + 1) ^ (ml & 7)) << 2;

  floatx4 acc[4][4] = {};

  for (int k0 = 0; k0 < K; k0 += 32) {
    __syncthreads();   // prior iter's LDS reads done before DMA overwrites
    if (A_F32) {
      const float* A = (const float*)Av;
      GLD_LDS16(A + (size_t)ar0 * K + k0 + fgo, AfU0);
      GLD_LDS16(A + (size_t)ar1 * K + k0 + fgo, AfU1);
      GLD_LDS16(A + (size_t)ar2 * K + k0 + fgo, AfU2);
      GLD_LDS16(A + (size_t)ar3 * K + k0 + fgo, AfU3);
    } else {
      const ushort* A = (const ushort*)Av;
      GLD_LDS16(A + (size_t)ar0 * K + k0 + bgo, AbU0);
      GLD_LDS16(A + (size_t)ar1 * K + k0 + bgo, AbU1);
    }
    GLD_LDS16(BT + (size_t)br0 * K + k0 + bgo, BsU0);
    GLD_LDS16(BT + (size_t)br1 * K + k0 + bgo, BsU1);
    __syncthreads();   // drains vmcnt (DMA complete) + barrier

    short8 af[4], bf[4];
#pragma unroll
    for (int i = 0; i < 4; i++) {
      const int R = wm + 16 * i + ml;
      if (A_F32) {
        const float* rb = Asf + R * 32;
        float4 lo = *(const float4*)(rb + qf_lo);
        float4 hi = *(const float4*)(rb + qf_hi);
        union { ushort u[8]; short8 s; } cv;
        cv.u[0] = f2b(lo.x); cv.u[1] = f2b(lo.y); cv.u[2] = f2b(lo.z); cv.u[3] = f2b(lo.w);
        cv.u[4] = f2b(hi.x); cv.u[5] = f2b(hi.y); cv.u[6] = f2b(hi.z); cv.u[7] = f2b(hi.w);
        af[i] = cv.s;
      } else {
        af[i] = *(const short8*)(Asb + R * 32 + qs_b);
      }
    }
#pragma unroll
    for (int j = 0; j < 4; j++)
      bf[j] = *(const short8*)(Bs + (wn + 16 * j + ml) * 32 + qs_b);
#pragma unroll
    for (int i = 0; i < 4; i++)
#pragma unroll
      for (int j = 0; j < 4; j++)
        acc[i][j] = __builtin_amdgcn_mfma_f32_16x16x32_bf16(af[i], bf[j], acc[i][j], 0, 0, 0);
  }

#pragma unroll
  for (int i = 0; i < 4; i++) {
#pragma unroll
    for (int j = 0; j < 4; j++) {
      int n = bn + wn + 16 * j + ml;      // C/D: col = lane&15  [m89 verified]
      if (n < F) {
        float bv = bias ? bias[n] : 0.0f;
#pragma unroll
        for (int r = 0; r < 4; r++) {
          int m = bm + wm + 16 * i + q * 4 + r;  // C/D: row = quad*4 + reg
          if (m < M) {
            float val = acc[i][j][r] + bv;
            if (OUT_F32) ((float*)Cv)[(size_t)m * F + n] = val;
            else         ((ushort*)Cv)[(size_t)m * F + n] = f2b(val);
          }
        }
      }
    }
  }
}

// ---------------- GCN aggregation: out[d] = relu(b + dinv_d^2*H[d] + sum_e dinv_s*dinv_d*H[s]) ----------------
// one wave per destination node; lane holds F/64 contiguous features. H bf16, out bf16, bias f32.
// Edge loop unrolled x8: ~17 outstanding VMEM ops/wave for latency hiding.
template<int F>
__global__ __launch_bounds__(256) void agg_kernel(const ushort* __restrict__ H,
                                                  const float* __restrict__ bias,
                                                  const float* __restrict__ dinv,
                                                  const int* __restrict__ rp,
                                                  const int* __restrict__ srcs,
                                                  ushort* __restrict__ out, int n) {
  constexpr int VPL = F / 64;
  int wid = blockIdx.x * 4 + (threadIdx.x >> 6);
  if (wid >= n) return;
  int lane = threadIdx.x & 63;
  int fo = lane * VPL;
  const ushort* Hf = H + fo;
  float invd = dinv[wid];
  float acc[VPL];
#pragma unroll
  for (int v = 0; v < VPL; v++) acc[v] = bias[fo + v];
  {
    float ws = invd * invd;
    if (VPL == 4) {
      ushort4 hv = *(const ushort4*)(Hf + (size_t)wid * F);
      acc[0] += ws * b2f(hv.x); acc[1] += ws * b2f(hv.y);
      acc[2] += ws * b2f(hv.z); acc[3] += ws * b2f(hv.w);
    } else {
      ushort2 hv = *(const ushort2*)(Hf + (size_t)wid * F);
      acc[0] += ws * b2f(hv.x); acc[1] += ws * b2f(hv.y);
    }
  }
  int p = rp[wid], p1 = rp[wid + 1];
  for (; p + 8 <= p1; p += 8) {
    int s[8];
#pragma unroll
    for (int u = 0; u < 8; u++) s[u] = srcs[p + u];
    float w[8];
#pragma unroll
    for (int u = 0; u < 8; u++) w[u] = dinv[s[u]] * invd;
    if (VPL == 4) {
      ushort4 h[8];
#pragma unroll
      for (int u = 0; u < 8; u++) h[u] = *(const ushort4*)(Hf + (size_t)s[u] * F);
#pragma unroll
      for (int u = 0; u < 8; u++) {
        acc[0] += w[u] * b2f(h[u].x); acc[1] += w[u] * b2f(h[u].y);
        acc[2] += w[u] * b2f(h[u].z); acc[3] += w[u] * b2f(h[u].w);
      }
    } else {
      ushort2 h[8];
#pragma unroll
      for (int u = 0; u < 8; u++) h[u] = *(const ushort2*)(Hf + (size_t)s[u] * F);
#pragma unroll
      for (int u = 0; u < 8; u++) {
        acc[0] += w[u] * b2f(h[u].x); acc[1] += w[u] * b2f(h[u].y);
      }
    }
  }
  for (; p < p1; ++p) {
    int s = srcs[p];
    float w = dinv[s] * invd;
    if (VPL == 4) {
      ushort4 hv = *(const ushort4*)(Hf + (size_t)s * F);
      acc[0] += w * b2f(hv.x); acc[1] += w * b2f(hv.y);
      acc[2] += w * b2f(hv.z); acc[3] += w * b2f(hv.w);
    } else {
      ushort2 hv = *(const ushort2*)(Hf + (size_t)s * F);
      acc[0] += w * b2f(hv.x); acc[1] += w * b2f(hv.y);
    }
  }
  ushort* op = out + (size_t)wid * F + fo;
#pragma unroll
  for (int v = 0; v < VPL; v++) op[v] = f2b(fmaxf(acc[v], 0.0f));
}

// ---------------- log_softmax over 64 classes: one wave per row, f32 in/out ----------------
__global__ __launch_bounds__(256) void logsoftmax_kernel(const float* __restrict__ logits,
                                                         float* __restrict__ out, int n) {
  int wid = blockIdx.x * 4 + (threadIdx.x >> 6);
  if (wid >= n) return;
  int lane = threadIdx.x & 63;
  float l = logits[(size_t)wid * 64 + lane];
  float m = l;
#pragma unroll
  for (int off = 32; off; off >>= 1) m = fmaxf(m, __shfl_xor(m, off, 64));
  float e = __expf(l - m);
#pragma unroll
  for (int off = 32; off; off >>= 1) e += __shfl_xor(e, off, 64);
  out[(size_t)wid * 64 + lane] = (l - m) - __logf(e);
}

// ---------------- launch ----------------

extern "C" void kernel_launch(void* const* d_in, const int* in_sizes, int n_in,
                              void* d_out, int out_size, void* d_ws, size_t ws_size,
                              hipStream_t stream) {
  const float* x  = (const float*)d_in[0];   // f32 per reference dtypes
  const int* ei   = (const int*)d_in[1];
  const float* W1 = (const float*)d_in[2];
  const float* b1 = (const float*)d_in[3];
  const float* W2 = (const float*)d_in[4];
  const float* b2 = (const float*)d_in[5];
  const float* Wc = (const float*)d_in[6];
  const float* bc = (const float*)d_in[7];

  const int N = in_sizes[0] / F_IN;
  const int E = in_sizes[1] / 2;
  const int* e_src = ei;
  const int* e_dst = ei + E;

  // workspace layout (256B aligned slices); total ~55.3 MB
  char* ws = (char*)d_ws;
  size_t off = 0;
  auto alloc = [&](size_t bytes) { char* p = ws + off; off += (bytes + 255) & ~(size_t)255; return p; };
  int*    cnt  = (int*)alloc((size_t)N * 4);
  float*  dinv = (float*)alloc((size_t)N * 4);
  int*    rp   = (int*)alloc((size_t)(N + 1) * 4);
  int*    part = (int*)alloc((size_t)1024 * 4);
  int*    srcs = (int*)alloc((size_t)E * 4);
  ushort* w1t  = (ushort*)alloc((size_t)F_HID * F_IN * 2);
  ushort* w2t  = (ushort*)alloc((size_t)F_MID * F_HID * 2);
  ushort* wct  = (ushort*)alloc((size_t)F_OUT * F_MID * 2);
  ushort* bufH = (ushort*)alloc((size_t)N * F_HID * 2);  // pre-agg H; reused as fp32 logits (N*64*4 == N*256 B <= N*512 B)
  ushort* bufG = (ushort*)alloc((size_t)N * F_HID * 2);  // post-agg h
  (void)ws_size; (void)n_in; (void)out_size;

  int gE = (E + 255) / 256, gW = (N + 3) / 4, gM = (N + 127) / 128;
  int nb = (N + 1023) / 1024;

  // CSR + dinv
  hipMemsetAsync(cnt, 0, (size_t)N * 4, stream);
  hist_kernel<<<gE, 256, 0, stream>>>(e_dst, cnt, E);
  dinv_kernel<<<(N + 255) / 256, 256, 0, stream>>>(cnt, dinv, N);
  scan1_kernel<<<nb, 1024, 0, stream>>>(cnt, rp, part, N);
  scan2_kernel<<<1, 1024, 0, stream>>>(part, rp, nb, N);
  scan3_kernel<<<nb, 1024, 0, stream>>>(part, rp, N);
  fill_kernel<<<gE, 256, 0, stream>>>(e_src, e_dst, rp, cnt, srcs, E);

  // weight transposes (f32 -> bf16 B^T layout)
  transpose_kernel<<<(F_IN * F_HID + 255) / 256, 256, 0, stream>>>(W1, w1t, F_IN, F_HID);
  transpose_kernel<<<(F_HID * F_MID + 255) / 256, 256, 0, stream>>>(W2, w2t, F_HID, F_MID);
  transpose_kernel<<<(F_MID * F_OUT + 255) / 256, 256, 0, stream>>>(Wc, wct, F_MID, F_OUT);

  // layer 1: H = x @ W1 (f32 A staged via global_load_lds) ; h1 = relu(agg(H) + b1)
  gemm_bt<true, false><<<dim3(gM, F_HID / 128), 256, 0, stream>>>(x, w1t, nullptr, bufH, N, F_IN, F_HID);
  agg_kernel<F_HID><<<gW, 256, 0, stream>>>(bufH, b1, dinv, rp, srcs, bufG, N);

  // layer 2: H2 = h1 @ W2 ; h2 = relu(agg(H2) + b2)
  gemm_bt<false, false><<<dim3(gM, 1), 256, 0, stream>>>(bufG, w2t, nullptr, bufH, N, F_HID, F_MID);
  agg_kernel<F_MID><<<gW, 256, 0, stream>>>(bufH, b2, dinv, rp, srcs, bufG, N);

  // classifier: logits = h2 @ Wc + bc (fp32, into bufH), then log_softmax -> d_out (f32)
  gemm_bt<false, true><<<dim3(gM, 1), 256, 0, stream>>>(bufG, wct, bc, (void*)bufH, N, F_MID, F_OUT);
  logsoftmax_kernel<<<gW, 256, 0, stream>>>((const float*)bufH, (float*)d_out, N);
}